// Round 7
// baseline (53.441 us; speedup 1.0000x reference)
//
#include <hip/hip_runtime.h>
#include <stdint.h>

// ---------------------------------------------------------------------------
// QFF radiance field forward, fully fused, f16 MFMA (gfx950 32x32x16).
// Swapped operands: D = W^T (A) @ X^T (B)  ->  D[out][point], col = point.
//
// Round-6 PMC arithmetic: LDS pipe was the bottleneck (28 b128 weight-frag
// reads + 48 b32 gather reads = ~614 cyc/iter/CU -> ~33us + 8us conflicts).
// Fix: weights staged LDS->registers ONCE per block (32 frags = 128 VGPRs,
// pinned with asm touch against rematerialization); loop now only gathers.
// __launch_bounds__(512,2): 256-reg budget fits ~210 demand, no spill.
// Grid f16 conversion MUST be RTN (static_cast), not v_cvt_pkrtz (RTZ):
// RTZ's coherent bias pushed absmax 3.9e-3 -> 1.95e-2 (round-4 failure).
// ---------------------------------------------------------------------------

typedef _Float16 half8  __attribute__((ext_vector_type(8)));
typedef _Float16 h2     __attribute__((ext_vector_type(2)));
typedef float    f32x16 __attribute__((ext_vector_type(16)));

union FragU { uint32_t u[4]; uint4 q; half8 h; };
union H2U   { uint32_t u; h2 h; };

static __device__ __forceinline__ h2 bch2(uint32_t v) { H2U x; x.u = v; return x.h; }
static __device__ __forceinline__ uint32_t bcu(h2 v)  { H2U x; x.h = v; return x.u; }

// cvt_pkrtz returns a __fp16 vector; bit-cast to our _Float16 vector type.
static __device__ __forceinline__ h2 cvtpk(float lo, float hi) {
  return __builtin_bit_cast(h2, __builtin_amdgcn_cvt_pkrtz(lo, hi));
}
static __device__ __forceinline__ uint32_t pkrtz(float lo, float hi) {
  return bcu(cvtpk(lo, hi));
}
// v_permlane32_swap_b32: after: a = [a_lo | b_lo], b = [a_hi | b_hi] (lane halves)
static __device__ __forceinline__ void plswap_u(uint32_t &a, uint32_t &b) {
  asm("v_permlane32_swap_b32 %0, %1" : "+v"(a), "+v"(b));
}
static __device__ __forceinline__ void plswap_f(float &a, float &b) {
  asm("v_permlane32_swap_b32 %0, %1" : "+v"(a), "+v"(b));
}
static __device__ __forceinline__ half8 mk_frag(uint32_t a, uint32_t b, uint32_t c, uint32_t d) {
  FragU f; f.u[0] = a; f.u[1] = b; f.u[2] = c; f.u[3] = d; return f.h;
}
static __device__ __forceinline__ uint32_t maxz(uint32_t v) {  // packed relu
  h2 h = bch2(v); h = __builtin_elementwise_max(h, (h2)(_Float16)0.0f); return bcu(h);
}
static __device__ __forceinline__ unsigned short f16b(float v) {  // RTN convert
  _Float16 h = (_Float16)v; return __builtin_bit_cast(unsigned short, h);
}

#define MFMA(A, B, C) __builtin_amdgcn_mfma_f32_32x32x16_f16((A), (B), (C), 0, 0, 0)

// ---- LDS layout (bytes) ----
// W^T f16, row = out, padded k-stride; strides are odd multiples of 16B.
#define W1OFF   0      // 64 rows x 208 B (kpad=104)  = 13312
#define W2OFF   13312  // 32 rows x 144 B (kpad=72)   = 4608   (outs 16..31 zero)
#define WC1OFF  17920  // 64 rows x  80 B (kpad=40)   = 5120   (k=31 zero)
#define WC2OFF  23040  // 64 rows x 144 B             = 9216
#define WC3OFF  32256  // 32 rows x 144 B             = 4608   (outs 3..31 zero)
#define GROFF   36864  // grid: per line, 80 dw (f0,f1) then 80 dw (f2,f3); 24 x 640 B
#define LDSZ    52224
#define WBYTES  36864

// Load one A-fragment from LDS and PIN it in registers (asm touch prevents
// the compiler from sinking/rematerializing the ds_read into the tile loop).
static __device__ __forceinline__ half8 ldwp(const unsigned char* s, int row, int off) {
  FragU f; f.q = *(const uint4*)(s + row + off);
  asm volatile("" : "+v"(f.u[0]), "+v"(f.u[1]), "+v"(f.u[2]), "+v"(f.u[3]));
  return f.h;
}

// D (rows BASE..BASE+7 of acc cover 16 outs) -> B-frag of next layer.
template<int BASE, bool RELU>
static __device__ __forceinline__ half8 packB(const f32x16& a) {
  uint32_t x = pkrtz(a[BASE + 0], a[BASE + 1]);
  uint32_t z = pkrtz(a[BASE + 2], a[BASE + 3]);
  uint32_t y = pkrtz(a[BASE + 4], a[BASE + 5]);
  uint32_t w = pkrtz(a[BASE + 6], a[BASE + 7]);
  if (RELU) { x = maxz(x); z = maxz(z); y = maxz(y); w = maxz(w); }
  plswap_u(x, y);
  plswap_u(z, w);
  return mk_frag(x, z, y, w);
}

// Coord J (0..11): jm = J%6 selects freq/dim slot; J>=6 is the cos block.
// gbase = GROFF + g*1280; per-J line offset is compile-time.
template<int J>
static __device__ __forceinline__ void gather(const float* m, int gbase,
                                              float q0, float q1, float q2,
                                              const unsigned char* lds,
                                              uint32_t& w01, uint32_t& w23) {
  constexpr int jm = J % 6;
  constexpr int DIMP[6] = {0, 1, 1, 2, 2, 0};
  constexpr int LNS0[6] = {0, 1, 4, 5, 8, 9};
  constexpr int GOFFJ = (LNS0[jm] + (J < 6 ? 0 : 12)) * 640;
  float q = (DIMP[jm] == 0) ? q0 : ((DIMP[jm] == 1) ? q1 : q2);
  float r = fmaf(q, m[jm], (J < 6) ? 0.0f : 0.25f);   // cos = sin(x + 1/4 rev)
  r = __builtin_amdgcn_fractf(r);
  float s = __builtin_amdgcn_sinf(r);
  float u = fmaf(s, 39.5f, 39.5f);       // (s+1)*0.5*79  in [0, 79]
  int i0 = (int)u;                        // trunc == floor (u >= 0)
  i0 = i0 < 0 ? 0 : (i0 > 78 ? 78 : i0);
  float w = u - (float)i0;
  const unsigned char* base = lds + gbase + GOFFJ + (i0 << 2);
  uint32_t a0 = *(const uint32_t*)(base);          // (f0,f1) @ i0
  uint32_t b0 = *(const uint32_t*)(base + 4);      // (f0,f1) @ i0+1
  uint32_t a1 = *(const uint32_t*)(base + 320);    // (f2,f3) @ i0
  uint32_t b1 = *(const uint32_t*)(base + 324);    // (f2,f3) @ i0+1
  h2 wh = cvtpk(w, w);
  h2 f01 = __builtin_elementwise_fma(bch2(b0) - bch2(a0), wh, bch2(a0));
  h2 f23 = __builtin_elementwise_fma(bch2(b1) - bch2(a1), wh, bch2(a1));
  w01 = bcu(f01);
  w23 = bcu(f23);
}

template<int T>
static __device__ __forceinline__ half8 enc2(const float* m, int gbase,
                                             float q0, float q1, float q2,
                                             const unsigned char* lds) {
  uint32_t a, b, c, d;
  gather<2 * T + 0>(m, gbase, q0, q1, q2, lds, a, b);
  gather<2 * T + 1>(m, gbase, q0, q1, q2, lds, c, d);
  return mk_frag(a, b, c, d);
}

__global__ __launch_bounds__(512, 2)
void qff_fwd(const float* __restrict__ pos, const float* __restrict__ dir,
             const float* __restrict__ grid,
             const float* __restrict__ w1, const float* __restrict__ w2,
             const float* __restrict__ wc1, const float* __restrict__ wc2,
             const float* __restrict__ wc3,
             float* __restrict__ out, int Npts) {
  __shared__ __align__(16) unsigned char smem[LDSZ];
  const int tid = threadIdx.x;

  // ---- stage weights (W^T, f16, frag-shaped) + grid (f16 pairs) into LDS ----
  for (int i = tid; i < WBYTES / 4; i += 512) ((uint32_t*)smem)[i] = 0;
  __syncthreads();
  for (int i = tid; i < 6144; i += 512)   // w1 [96][64]
    *(unsigned short*)(smem + W1OFF  + (i & 63) * 208 + (i >> 6) * 2) = f16b(w1[i]);
  for (int i = tid; i < 1024; i += 512)   // w2 [64][16]
    *(unsigned short*)(smem + W2OFF  + (i & 15) * 144 + (i >> 4) * 2) = f16b(w2[i]);
  for (int i = tid; i < 1984; i += 512)   // wc1 [31][64]
    *(unsigned short*)(smem + WC1OFF + (i & 63) * 80  + (i >> 6) * 2) = f16b(wc1[i]);
  for (int i = tid; i < 4096; i += 512)   // wc2 [64][64]
    *(unsigned short*)(smem + WC2OFF + (i & 63) * 144 + (i >> 6) * 2) = f16b(wc2[i]);
  for (int i = tid; i < 192; i += 512)    // wc3 [64][3]
    *(unsigned short*)(smem + WC3OFF + (i % 3) * 144 + (i / 3) * 2) = f16b(wc3[i]);
  for (int i = tid; i < 1920; i += 512) { // grid [24][80][4] f32 -> dword pairs, RTN
    float4 v = ((const float4*)grid)[i];
    int line = i / 80, q = i - line * 80;
    uint32_t* dst = (uint32_t*)(smem + GROFF + line * 640 + q * 4);
    dst[0]  = (((uint32_t)f16b(v.y)) << 16) | f16b(v.x);   // f01 sub-array
    dst[80] = (((uint32_t)f16b(v.w)) << 16) | f16b(v.z);   // f23 sub-array (+320 B)
  }
  __syncthreads();

  const int lane = tid & 63;
  const int wid  = tid >> 6;          // 0..7
  const int g    = lane >> 5;
  const int o    = lane & 31;

  // ---- one-time: hoist all 32 weight A-fragments LDS -> registers ----
  const int a13 = o * 208 + g * 16;
  const int a9  = o * 144 + g * 16;
  const int a5  = o * 80  + g * 16;
  half8 w1f[2][6], w2f[4], c1f[2][2], c2f[2][4], c3f[4];
#pragma unroll
  for (int t = 0; t < 6; ++t) {
    w1f[0][t] = ldwp(smem, a13, W1OFF + t * 32);
    w1f[1][t] = ldwp(smem, a13, W1OFF + 6656 + t * 32);
  }
#pragma unroll
  for (int t = 0; t < 4; ++t) {
    w2f[t]    = ldwp(smem, a9, W2OFF + t * 32);
    c2f[0][t] = ldwp(smem, a9, WC2OFF + t * 32);
    c2f[1][t] = ldwp(smem, a9, WC2OFF + 4608 + t * 32);
    c3f[t]    = ldwp(smem, a9, WC3OFF + t * 32);
  }
#pragma unroll
  for (int t = 0; t < 2; ++t) {
    c1f[0][t] = ldwp(smem, a5, WC1OFF + t * 32);
    c1f[1][t] = ldwp(smem, a5, WC1OFF + 2560 + t * 32);
  }

  // ---- per-lane constants ----
  constexpr float IV = 0.15915494309189535f;
  constexpr float F0 = 2.0f, F1 = 6.349604207872798f, F2 = 20.158736798317971f, F3 = 64.0f;
  const float M0c[6] = {F0*IV, F0*IV, F1*IV, F1*IV, F2*IV, F3*IV};
  const float M1c[6] = {F0*IV, F1*IV, F2*IV, F2*IV, F3*IV, F3*IV};
  float m[6];
#pragma unroll
  for (int j = 0; j < 6; ++j) m[j] = g ? M1c[j] : M0c[j];
  const int gbase = GROFF + g * 1280;   // line block base (lines 2g*...)

  const f32x16 Z = {0,0,0,0, 0,0,0,0, 0,0,0,0, 0,0,0,0};
  const int ntile = Npts >> 8;   // 256 points per block-tile (8 waves x 32)
  int tb = blockIdx.x;
  if (tb >= ntile) return;

  int p = (tb << 8) + (wid << 5) + o;
  float px = pos[3*p+0], py = pos[3*p+1], pz = pos[3*p+2];
  float dx = dir[3*p+0], dy = dir[3*p+1], dz = dir[3*p+2];

  for (; tb < ntile; tb += gridDim.x) {
    // prefetch next tile's point data (lands during the MLP below)
    int tbn = tb + gridDim.x;
    int pn  = ((tbn < ntile ? tbn : ntile - 1) << 8) + (wid << 5) + o;
    float npx = pos[3*pn+0], npy = pos[3*pn+1], npz = pos[3*pn+2];
    float ndx = dir[3*pn+0], ndy = dir[3*pn+1], ndz = dir[3*pn+2];

    // q-rotation: makes the dim pattern identical for both lane halves
    float q0 = g ? pz : px;
    float q1 = g ? px : py;
    float q2 = g ? py : pz;

    // ---- L1: enc(96) @ w_geom1 -> h1(64) ----
    f32x16 acc0 = Z, acc1 = Z;
#define L1STEP(T) { half8 bf = enc2<T>(m, gbase, q0, q1, q2, smem); \
                    acc0 = MFMA(w1f[0][T], bf, acc0); \
                    acc1 = MFMA(w1f[1][T], bf, acc1); }
    L1STEP(0) L1STEP(1) L1STEP(2) L1STEP(3) L1STEP(4) L1STEP(5)
#undef L1STEP

    half8 hb0 = packB<0, true>(acc0), hb1 = packB<8, true>(acc0);
    half8 hb2 = packB<0, true>(acc1), hb3 = packB<8, true>(acc1);

    // ---- L2: h1 @ w_geom2 -> f(16), no relu ----
    f32x16 acc2 = Z;
    acc2 = MFMA(w2f[0], hb0, acc2);
    acc2 = MFMA(w2f[1], hb1, acc2);
    acc2 = MFMA(w2f[2], hb2, acc2);
    acc2 = MFMA(w2f[3], hb3, acc2);
    float sigma = __expf(acc2[0] - 1.0f);   // g==0 lanes: reg0 = out0 = raw_sigma

    // ---- spherical harmonics: lane half g supplies sh[8g..8g+7] ----
    float xx = dx*dx, yy = dy*dy, zz = dz*dz;
    float xy = dx*dy, yz = dy*dz, xz = dx*dz;
    float s0, s1, s2, s3, s4, s5, s6, s7;
    if (g == 0) {
      s0 = 0.28209479177387814f;
      s1 = -0.48860251190291987f * dy;
      s2 =  0.48860251190291987f * dz;
      s3 = -0.48860251190291987f * dx;
      s4 =  1.0925484305920792f * xy;
      s5 = -1.0925484305920792f * yz;
      s6 =  0.94617469575756f * zz - 0.31539156525252f;
      s7 = -1.0925484305920792f * xz;
    } else {
      s0 =  0.5462742152960396f * (xx - yy);
      s1 = -0.5900435899266435f * dy * (3.0f * xx - yy);
      s2 =  2.890611442640554f * xy * dz;
      s3 = -0.4570457994644657f * dy * (4.0f * zz - xx - yy);
      s4 =  0.37317633259011546f * dz * (2.0f * zz - 3.0f * xx - 3.0f * yy);
      s5 = -0.4570457994644657f * dx * (4.0f * zz - xx - yy);
      s6 =  1.445305721320277f * dz * (xx - yy);
      s7 = -0.5900435899266435f * dx * (xx - 3.0f * yy);
    }
    half8 shB = mk_frag(pkrtz(s0, s1), pkrtz(s2, s3), pkrtz(s4, s5), pkrtz(s6, s7));

    // ---- feature = f[1..15] -> hc k 16..30 (k=31 hits zeroed wc1 row) ----
    uint32_t e0 = pkrtz(acc2[1], acc2[2]);
    uint32_t e2 = pkrtz(acc2[5], acc2[6]);
    plswap_u(e0, e2);
    float a3 = acc2[3], b7 = acc2[7];
    plswap_f(a3, b7);
    float cc0 = acc2[0], d4 = acc2[4];
    plswap_f(cc0, d4);
    uint32_t e1 = pkrtz(a3, d4);
    uint32_t e3 = pkrtz(b7, acc2[4]);
    half8 featB = mk_frag(e0, e1, e2, e3);

    // ---- L3: hc(32) @ w_color1 -> h2(64), relu ----
    f32x16 acc3a = Z, acc3b = Z;
    acc3a = MFMA(c1f[0][0], shB,   acc3a);
    acc3a = MFMA(c1f[0][1], featB, acc3a);
    acc3b = MFMA(c1f[1][0], shB,   acc3b);
    acc3b = MFMA(c1f[1][1], featB, acc3b);

    half8 g2b0 = packB<0, true>(acc3a), g2b1 = packB<8, true>(acc3a);
    half8 g2b2 = packB<0, true>(acc3b), g2b3 = packB<8, true>(acc3b);

    // ---- L4: h2 @ w_color2 -> h3(64), relu ----
    f32x16 acc4a = Z, acc4b = Z;
    acc4a = MFMA(c2f[0][0], g2b0, acc4a);
    acc4a = MFMA(c2f[0][1], g2b1, acc4a);
    acc4a = MFMA(c2f[0][2], g2b2, acc4a);
    acc4a = MFMA(c2f[0][3], g2b3, acc4a);
    acc4b = MFMA(c2f[1][0], g2b0, acc4b);
    acc4b = MFMA(c2f[1][1], g2b1, acc4b);
    acc4b = MFMA(c2f[1][2], g2b2, acc4b);
    acc4b = MFMA(c2f[1][3], g2b3, acc4b);

    half8 g3b0 = packB<0, true>(acc4a), g3b1 = packB<8, true>(acc4a);
    half8 g3b2 = packB<0, true>(acc4b), g3b3 = packB<8, true>(acc4b);

    // ---- L5: h3 @ w_color3 -> rgb(3), sigmoid ----
    f32x16 acc5 = Z;
    acc5 = MFMA(c3f[0], g3b0, acc5);
    acc5 = MFMA(c3f[1], g3b1, acc5);
    acc5 = MFMA(c3f[2], g3b2, acc5);
    acc5 = MFMA(c3f[3], g3b3, acc5);

    if (lane < 32) {   // g==0 lanes hold outs 0..3 in regs 0..3
      float rr = __builtin_amdgcn_rcpf(1.0f + __expf(-acc5[0]));
      float gg = __builtin_amdgcn_rcpf(1.0f + __expf(-acc5[1]));
      float bb = __builtin_amdgcn_rcpf(1.0f + __expf(-acc5[2]));
      out[3 * p + 0] = rr;
      out[3 * p + 1] = gg;
      out[3 * p + 2] = bb;
      out[3 * Npts + p] = sigma;
    }

    p = pn;
    px = npx; py = npy; pz = npz;
    dx = ndx; dy = ndy; dz = ndz;
  }
}

extern "C" void kernel_launch(void* const* d_in, const int* in_sizes, int n_in,
                              void* d_out, int out_size, void* d_ws, size_t ws_size,
                              hipStream_t stream) {
  const float* pos  = (const float*)d_in[0];
  const float* dirs = (const float*)d_in[1];
  const float* grid = (const float*)d_in[2];
  const float* w1   = (const float*)d_in[3];
  const float* w2   = (const float*)d_in[4];
  const float* wc1  = (const float*)d_in[5];
  const float* wc2  = (const float*)d_in[6];
  const float* wc3  = (const float*)d_in[7];
  float* out = (float*)d_out;
  const int Npts = in_sizes[0] / 3;

  qff_fwd<<<dim3(512), dim3(512), 0, stream>>>(pos, dirs, grid, w1, w2, wc1, wc2, wc3,
                                               out, Npts);
}

// Round 8
// 49.141 us; speedup vs baseline: 1.0875x; 1.0875x over previous
//
#include <hip/hip_runtime.h>
#include <stdint.h>

// ---------------------------------------------------------------------------
// QFF radiance field forward, fully fused, f16 MFMA (gfx950 32x32x16).
// Swapped operands: D = W^T (A) @ X^T (B)  ->  D[out][point], col = point.
// Weights in LDS in fragment-shaped f16 layout (one ds_read_b128 per
// A-fragment). Grid in LDS as per-line interleaved dword arrays. Activations
// stay in registers: D -> next B via v_cvt_pkrtz + v_permlane32_swap_b32.
//
// Residency ledger (512-thr blocks): VGPR 64 -> reg tier allows 24 waves/CU;
// LDS 52224 B -> 3 blocks/CU (156.7 KB <= 160 KB). Grid 768 = 3 blocks/CU
// resident, 24 waves/CU. Round 7 showed the hoist trap: (512,2) = 1 block/CU.
// Grid f16 conversion MUST be RTN (static_cast), not v_cvt_pkrtz (RTZ):
// RTZ's coherent bias pushed absmax 3.9e-3 -> 1.95e-2 (round-4 failure).
// ---------------------------------------------------------------------------

typedef _Float16 half8  __attribute__((ext_vector_type(8)));
typedef _Float16 h2     __attribute__((ext_vector_type(2)));
typedef float    f32x16 __attribute__((ext_vector_type(16)));

union FragU { uint32_t u[4]; uint4 q; half8 h; };
union H2U   { uint32_t u; h2 h; };

static __device__ __forceinline__ h2 bch2(uint32_t v) { H2U x; x.u = v; return x.h; }
static __device__ __forceinline__ uint32_t bcu(h2 v)  { H2U x; x.h = v; return x.u; }

// cvt_pkrtz returns a __fp16 vector; bit-cast to our _Float16 vector type.
static __device__ __forceinline__ h2 cvtpk(float lo, float hi) {
  return __builtin_bit_cast(h2, __builtin_amdgcn_cvt_pkrtz(lo, hi));
}
static __device__ __forceinline__ uint32_t pkrtz(float lo, float hi) {
  return bcu(cvtpk(lo, hi));
}
// v_permlane32_swap_b32: after: a = [a_lo | b_lo], b = [a_hi | b_hi] (lane halves)
static __device__ __forceinline__ void plswap_u(uint32_t &a, uint32_t &b) {
  asm("v_permlane32_swap_b32 %0, %1" : "+v"(a), "+v"(b));
}
static __device__ __forceinline__ void plswap_f(float &a, float &b) {
  asm("v_permlane32_swap_b32 %0, %1" : "+v"(a), "+v"(b));
}
static __device__ __forceinline__ half8 mk_frag(uint32_t a, uint32_t b, uint32_t c, uint32_t d) {
  FragU f; f.u[0] = a; f.u[1] = b; f.u[2] = c; f.u[3] = d; return f.h;
}
static __device__ __forceinline__ uint32_t maxz(uint32_t v) {  // packed relu
  h2 h = bch2(v); h = __builtin_elementwise_max(h, (h2)(_Float16)0.0f); return bcu(h);
}
static __device__ __forceinline__ unsigned short f16b(float v) {  // RTN convert
  _Float16 h = (_Float16)v; return __builtin_bit_cast(unsigned short, h);
}

#define MFMA(A, B, C) __builtin_amdgcn_mfma_f32_32x32x16_f16((A), (B), (C), 0, 0, 0)

// ---- LDS layout (bytes) ----
// W^T f16, row = out, padded k-stride; strides are odd multiples of 16B.
#define W1OFF   0      // 64 rows x 208 B (kpad=104)  = 13312
#define W2OFF   13312  // 32 rows x 144 B (kpad=72)   = 4608   (outs 16..31 zero)
#define WC1OFF  17920  // 64 rows x  80 B (kpad=40)   = 5120   (k=31 zero)
#define WC2OFF  23040  // 64 rows x 144 B             = 9216
#define WC3OFF  32256  // 32 rows x 144 B             = 4608   (outs 3..31 zero)
#define GROFF   36864  // grid: per line, 80 dw (f0,f1) then 80 dw (f2,f3); 24 x 640 B
#define LDSZ    52224
#define WBYTES  36864

static __device__ __forceinline__ half8 ldw(const unsigned char* s, int row, int off) {
  FragU f; f.q = *(const uint4*)(s + row + off); return f.h;
}

// D (rows BASE..BASE+7 of acc cover 16 outs) -> B-frag of next layer.
template<int BASE, bool RELU>
static __device__ __forceinline__ half8 packB(const f32x16& a) {
  uint32_t x = pkrtz(a[BASE + 0], a[BASE + 1]);
  uint32_t z = pkrtz(a[BASE + 2], a[BASE + 3]);
  uint32_t y = pkrtz(a[BASE + 4], a[BASE + 5]);
  uint32_t w = pkrtz(a[BASE + 6], a[BASE + 7]);
  if (RELU) { x = maxz(x); z = maxz(z); y = maxz(y); w = maxz(w); }
  plswap_u(x, y);
  plswap_u(z, w);
  return mk_frag(x, z, y, w);
}

struct Pre {
  float m[6];     // freq/(2pi) per coord slot (period-6)
  int   gbs[12];  // byte base in LDS of this coord's line block (J = 0..11)
  int   a13, a9, a5;  // per-lane weight row offsets (+16*g folded in)
};

// Coord J (0..11): jm = J%6 selects freq/dim slot; J>=6 is the cos block.
template<int J>
static __device__ __forceinline__ void gather(const Pre& pre, float q0, float q1, float q2,
                                              const unsigned char* lds,
                                              uint32_t& w01, uint32_t& w23) {
  constexpr int jm = J % 6;
  constexpr int DIMP[6] = {0, 1, 1, 2, 2, 0};
  float q = (DIMP[jm] == 0) ? q0 : ((DIMP[jm] == 1) ? q1 : q2);
  float r = fmaf(q, pre.m[jm], (J < 6) ? 0.0f : 0.25f);   // cos = sin(x + 1/4 rev)
  r = __builtin_amdgcn_fractf(r);
  float s = __builtin_amdgcn_sinf(r);
  float u = fmaf(s, 39.5f, 39.5f);       // (s+1)*0.5*79  in [0, 79]
  int i0 = (int)u;                        // trunc == floor (u >= 0)
  i0 = i0 < 0 ? 0 : (i0 > 78 ? 78 : i0);
  float w = u - (float)i0;
  const unsigned char* base = lds + pre.gbs[J] + (i0 << 2);
  uint32_t a0 = *(const uint32_t*)(base);          // (f0,f1) @ i0
  uint32_t b0 = *(const uint32_t*)(base + 4);      // (f0,f1) @ i0+1
  uint32_t a1 = *(const uint32_t*)(base + 320);    // (f2,f3) @ i0
  uint32_t b1 = *(const uint32_t*)(base + 324);    // (f2,f3) @ i0+1
  h2 wh = cvtpk(w, w);
  h2 f01 = __builtin_elementwise_fma(bch2(b0) - bch2(a0), wh, bch2(a0));
  h2 f23 = __builtin_elementwise_fma(bch2(b1) - bch2(a1), wh, bch2(a1));
  w01 = bcu(f01);
  w23 = bcu(f23);
}

template<int T>
static __device__ __forceinline__ half8 enc2(const Pre& pre, float q0, float q1, float q2,
                                             const unsigned char* lds) {
  uint32_t a, b, c, d;
  gather<2 * T + 0>(pre, q0, q1, q2, lds, a, b);
  gather<2 * T + 1>(pre, q0, q1, q2, lds, c, d);
  return mk_frag(a, b, c, d);
}

__global__ __launch_bounds__(512, 4)
void qff_fwd(const float* __restrict__ pos, const float* __restrict__ dir,
             const float* __restrict__ grid,
             const float* __restrict__ w1, const float* __restrict__ w2,
             const float* __restrict__ wc1, const float* __restrict__ wc2,
             const float* __restrict__ wc3,
             float* __restrict__ out, int Npts) {
  __shared__ __align__(16) unsigned char smem[LDSZ];
  const int tid = threadIdx.x;

  // ---- stage weights (W^T, f16, frag-shaped) + grid (f16 pairs) into LDS ----
  for (int i = tid; i < WBYTES / 4; i += 512) ((uint32_t*)smem)[i] = 0;
  __syncthreads();
  for (int i = tid; i < 6144; i += 512)   // w1 [96][64]
    *(unsigned short*)(smem + W1OFF  + (i & 63) * 208 + (i >> 6) * 2) = f16b(w1[i]);
  for (int i = tid; i < 1024; i += 512)   // w2 [64][16]
    *(unsigned short*)(smem + W2OFF  + (i & 15) * 144 + (i >> 4) * 2) = f16b(w2[i]);
  for (int i = tid; i < 1984; i += 512)   // wc1 [31][64]
    *(unsigned short*)(smem + WC1OFF + (i & 63) * 80  + (i >> 6) * 2) = f16b(wc1[i]);
  for (int i = tid; i < 4096; i += 512)   // wc2 [64][64]
    *(unsigned short*)(smem + WC2OFF + (i & 63) * 144 + (i >> 6) * 2) = f16b(wc2[i]);
  for (int i = tid; i < 192; i += 512)    // wc3 [64][3]
    *(unsigned short*)(smem + WC3OFF + (i % 3) * 144 + (i / 3) * 2) = f16b(wc3[i]);
  for (int i = tid; i < 1920; i += 512) { // grid [24][80][4] f32 -> dword pairs, RTN
    float4 v = ((const float4*)grid)[i];
    int line = i / 80, q = i - line * 80;
    uint32_t* dst = (uint32_t*)(smem + GROFF + line * 640 + q * 4);
    dst[0]  = (((uint32_t)f16b(v.y)) << 16) | f16b(v.x);   // f01 sub-array
    dst[80] = (((uint32_t)f16b(v.w)) << 16) | f16b(v.z);   // f23 sub-array (+320 B)
  }
  __syncthreads();

  const int lane = tid & 63;
  const int wid  = tid >> 6;          // 0..7
  const int g    = lane >> 5;
  const int o    = lane & 31;

  // ---- per-lane constants ----
  constexpr float IV = 0.15915494309189535f;
  constexpr float F0 = 2.0f, F1 = 6.349604207872798f, F2 = 20.158736798317971f, F3 = 64.0f;
  const float M0c[6] = {F0*IV, F0*IV, F1*IV, F1*IV, F2*IV, F3*IV};
  const float M1c[6] = {F0*IV, F1*IV, F2*IV, F2*IV, F3*IV, F3*IV};
  const int   LNS0[6] = {0, 1, 4, 5, 8, 9};
  const int   LNS1[6] = {2, 3, 6, 7, 10, 11};
  Pre pre;
#pragma unroll
  for (int j = 0; j < 6; ++j) {
    pre.m[j] = g ? M1c[j] : M0c[j];
    int ln = g ? LNS1[j] : LNS0[j];
    pre.gbs[j]     = GROFF + ln * 640;          // sin lines
    pre.gbs[j + 6] = GROFF + (ln + 12) * 640;   // cos lines
  }
  pre.a13 = o * 208 + g * 16;
  pre.a9  = o * 144 + g * 16;
  pre.a5  = o * 80  + g * 16;

  const f32x16 Z = {0,0,0,0, 0,0,0,0, 0,0,0,0, 0,0,0,0};
  const int ntile = Npts >> 8;   // 256 points per block-tile (8 waves x 32)
  int tb = blockIdx.x;
  if (tb >= ntile) return;

  int p = (tb << 8) + (wid << 5) + o;
  float px = pos[3*p+0], py = pos[3*p+1], pz = pos[3*p+2];
  float dx = dir[3*p+0], dy = dir[3*p+1], dz = dir[3*p+2];

  for (; tb < ntile; tb += gridDim.x) {
    // prefetch next tile's point data (lands during the MLP below)
    int tbn = tb + gridDim.x;
    int pn  = ((tbn < ntile ? tbn : ntile - 1) << 8) + (wid << 5) + o;
    float npx = pos[3*pn+0], npy = pos[3*pn+1], npz = pos[3*pn+2];
    float ndx = dir[3*pn+0], ndy = dir[3*pn+1], ndz = dir[3*pn+2];

    // q-rotation: makes the dim pattern identical for both lane halves
    float q0 = g ? pz : px;
    float q1 = g ? px : py;
    float q2 = g ? py : pz;

    // ---- L1: enc(96) @ w_geom1 -> h1(64) ----
    f32x16 acc0 = Z, acc1 = Z;
#define L1STEP(T) { half8 bf = enc2<T>(pre, q0, q1, q2, smem); \
                    acc0 = MFMA(ldw(smem, pre.a13, W1OFF + T*32), bf, acc0); \
                    acc1 = MFMA(ldw(smem, pre.a13, W1OFF + 6656 + T*32), bf, acc1); }
    L1STEP(0) L1STEP(1) L1STEP(2) L1STEP(3) L1STEP(4) L1STEP(5)
#undef L1STEP

    half8 hb0 = packB<0, true>(acc0), hb1 = packB<8, true>(acc0);
    half8 hb2 = packB<0, true>(acc1), hb3 = packB<8, true>(acc1);

    // ---- L2: h1 @ w_geom2 -> f(16), no relu ----
    f32x16 acc2 = Z;
    acc2 = MFMA(ldw(smem, pre.a9, W2OFF +  0), hb0, acc2);
    acc2 = MFMA(ldw(smem, pre.a9, W2OFF + 32), hb1, acc2);
    acc2 = MFMA(ldw(smem, pre.a9, W2OFF + 64), hb2, acc2);
    acc2 = MFMA(ldw(smem, pre.a9, W2OFF + 96), hb3, acc2);
    float sigma = __expf(acc2[0] - 1.0f);   // g==0 lanes: reg0 = out0 = raw_sigma

    // ---- spherical harmonics: lane half g supplies sh[8g..8g+7] ----
    float xx = dx*dx, yy = dy*dy, zz = dz*dz;
    float xy = dx*dy, yz = dy*dz, xz = dx*dz;
    float s0, s1, s2, s3, s4, s5, s6, s7;
    if (g == 0) {
      s0 = 0.28209479177387814f;
      s1 = -0.48860251190291987f * dy;
      s2 =  0.48860251190291987f * dz;
      s3 = -0.48860251190291987f * dx;
      s4 =  1.0925484305920792f * xy;
      s5 = -1.0925484305920792f * yz;
      s6 =  0.94617469575756f * zz - 0.31539156525252f;
      s7 = -1.0925484305920792f * xz;
    } else {
      s0 =  0.5462742152960396f * (xx - yy);
      s1 = -0.5900435899266435f * dy * (3.0f * xx - yy);
      s2 =  2.890611442640554f * xy * dz;
      s3 = -0.4570457994644657f * dy * (4.0f * zz - xx - yy);
      s4 =  0.37317633259011546f * dz * (2.0f * zz - 3.0f * xx - 3.0f * yy);
      s5 = -0.4570457994644657f * dx * (4.0f * zz - xx - yy);
      s6 =  1.445305721320277f * dz * (xx - yy);
      s7 = -0.5900435899266435f * dx * (xx - 3.0f * yy);
    }
    half8 shB = mk_frag(pkrtz(s0, s1), pkrtz(s2, s3), pkrtz(s4, s5), pkrtz(s6, s7));

    // ---- feature = f[1..15] -> hc k 16..30 (k=31 hits zeroed wc1 row) ----
    uint32_t e0 = pkrtz(acc2[1], acc2[2]);
    uint32_t e2 = pkrtz(acc2[5], acc2[6]);
    plswap_u(e0, e2);
    float a3 = acc2[3], b7 = acc2[7];
    plswap_f(a3, b7);
    float cc0 = acc2[0], d4 = acc2[4];
    plswap_f(cc0, d4);
    uint32_t e1 = pkrtz(a3, d4);
    uint32_t e3 = pkrtz(b7, acc2[4]);
    half8 featB = mk_frag(e0, e1, e2, e3);

    // ---- L3: hc(32) @ w_color1 -> h2(64), relu ----
    f32x16 acc3a = Z, acc3b = Z;
    acc3a = MFMA(ldw(smem, pre.a5, WC1OFF +  0), shB,   acc3a);
    acc3a = MFMA(ldw(smem, pre.a5, WC1OFF + 32), featB, acc3a);
    acc3b = MFMA(ldw(smem, pre.a5, WC1OFF + 2560 +  0), shB,   acc3b);
    acc3b = MFMA(ldw(smem, pre.a5, WC1OFF + 2560 + 32), featB, acc3b);

    half8 g2b0 = packB<0, true>(acc3a), g2b1 = packB<8, true>(acc3a);
    half8 g2b2 = packB<0, true>(acc3b), g2b3 = packB<8, true>(acc3b);

    // ---- L4: h2 @ w_color2 -> h3(64), relu ----
    f32x16 acc4a = Z, acc4b = Z;
    acc4a = MFMA(ldw(smem, pre.a9, WC2OFF +  0), g2b0, acc4a);
    acc4a = MFMA(ldw(smem, pre.a9, WC2OFF + 32), g2b1, acc4a);
    acc4a = MFMA(ldw(smem, pre.a9, WC2OFF + 64), g2b2, acc4a);
    acc4a = MFMA(ldw(smem, pre.a9, WC2OFF + 96), g2b3, acc4a);
    acc4b = MFMA(ldw(smem, pre.a9, WC2OFF + 4608 +  0), g2b0, acc4b);
    acc4b = MFMA(ldw(smem, pre.a9, WC2OFF + 4608 + 32), g2b1, acc4b);
    acc4b = MFMA(ldw(smem, pre.a9, WC2OFF + 4608 + 64), g2b2, acc4b);
    acc4b = MFMA(ldw(smem, pre.a9, WC2OFF + 4608 + 96), g2b3, acc4b);

    half8 g3b0 = packB<0, true>(acc4a), g3b1 = packB<8, true>(acc4a);
    half8 g3b2 = packB<0, true>(acc4b), g3b3 = packB<8, true>(acc4b);

    // ---- L5: h3 @ w_color3 -> rgb(3), sigmoid ----
    f32x16 acc5 = Z;
    acc5 = MFMA(ldw(smem, pre.a9, WC3OFF +  0), g3b0, acc5);
    acc5 = MFMA(ldw(smem, pre.a9, WC3OFF + 32), g3b1, acc5);
    acc5 = MFMA(ldw(smem, pre.a9, WC3OFF + 64), g3b2, acc5);
    acc5 = MFMA(ldw(smem, pre.a9, WC3OFF + 96), g3b3, acc5);

    if (lane < 32) {   // g==0 lanes hold outs 0..3 in regs 0..3
      float rr = __builtin_amdgcn_rcpf(1.0f + __expf(-acc5[0]));
      float gg = __builtin_amdgcn_rcpf(1.0f + __expf(-acc5[1]));
      float bb = __builtin_amdgcn_rcpf(1.0f + __expf(-acc5[2]));
      out[3 * p + 0] = rr;
      out[3 * p + 1] = gg;
      out[3 * p + 2] = bb;
      out[3 * Npts + p] = sigma;
    }

    p = pn;
    px = npx; py = npy; pz = npz;
    dx = ndx; dy = ndy; dz = ndz;
  }
}

extern "C" void kernel_launch(void* const* d_in, const int* in_sizes, int n_in,
                              void* d_out, int out_size, void* d_ws, size_t ws_size,
                              hipStream_t stream) {
  const float* pos  = (const float*)d_in[0];
  const float* dirs = (const float*)d_in[1];
  const float* grid = (const float*)d_in[2];
  const float* w1   = (const float*)d_in[3];
  const float* w2   = (const float*)d_in[4];
  const float* wc1  = (const float*)d_in[5];
  const float* wc2  = (const float*)d_in[6];
  const float* wc3  = (const float*)d_in[7];
  float* out = (float*)d_out;
  const int Npts = in_sizes[0] / 3;

  qff_fwd<<<dim3(768), dim3(512), 0, stream>>>(pos, dirs, grid, w1, w2, wc1, wc2, wc3,
                                               out, Npts);
}